// Round 1
// baseline (702.303 us; speedup 1.0000x reference)
//
#include <hip/hip_runtime.h>
#include <math.h>

// MultiGaitAdapter: causal TCN (2 blocks) + per-task head, but only y[:,:,-1]
// is consumed -> compute only the receptive-field window:
//   x times 231..255 (25) -> h0 235..255 (21) -> y0 239..255 odd (9)
//   -> h1 247..255 odd (5) -> y1 @255 -> head.  ~12.6 GFLOP vs 813 GFLOP full.

#define B_TOT 4096
#define CIN   30
#define LSEQ  256
#define C1    100
#define C2    200
#define KW    5
#define T0    231   // first x timestep needed
#define WIN   25    // x window length
#define NT_H0 21
#define NT_Y0 9
#define NT_H1 5

// ---------------- Kernel 1: h0 = relu(conv1_0(x)) on window -----------------
#define NB1 4
__global__ __launch_bounds__(256) void k_h0(const float* __restrict__ x,
                                            const float* __restrict__ w1,
                                            const float* __restrict__ b1,
                                            float* __restrict__ h0) {
  __shared__ float xs[NB1 * CIN * WIN];  // 3000 floats = 12 KB
  const int b0 = blockIdx.x * NB1;
  const int tid = threadIdx.x;
  for (int idx = tid; idx < NB1 * CIN * WIN; idx += 256) {
    int b = idx / (CIN * WIN);
    int r = idx - b * (CIN * WIN);
    int ci = r / WIN;
    int u = r - ci * WIN;
    xs[idx] = x[(size_t)(b0 + b) * (CIN * LSEQ) + ci * LSEQ + T0 + u];
  }
  __syncthreads();
  const int bl = tid & (NB1 - 1);
  const int cg = tid >> 2;  // 0..63
  const float* xb = xs + bl * (CIN * WIN);
  const int c0 = cg;
  const bool has2 = (cg < C1 - 64);  // cg < 36
  const int c1 = has2 ? cg + 64 : cg;

  float acc0[NT_H0], acc1[NT_H0];
  const float bias0 = b1[c0], bias1 = b1[c1];
#pragma unroll
  for (int i = 0; i < NT_H0; ++i) { acc0[i] = bias0; acc1[i] = bias1; }
  const float* wr0 = w1 + c0 * (CIN * KW);
  const float* wr1 = w1 + c1 * (CIN * KW);
  for (int ci = 0; ci < CIN; ++ci) {
    float xr[WIN];
#pragma unroll
    for (int u = 0; u < WIN; ++u) xr[u] = xb[ci * WIN + u];
#pragma unroll
    for (int k = 0; k < KW; ++k) {
      const float wa = wr0[ci * KW + k];
      const float wb = wr1[ci * KW + k];
#pragma unroll
      for (int i = 0; i < NT_H0; ++i) {
        acc0[i] = fmaf(xr[i + k], wa, acc0[i]);
        acc1[i] = fmaf(xr[i + k], wb, acc1[i]);
      }
    }
  }
  float* o0 = h0 + (size_t)(b0 + bl) * (C1 * NT_H0) + c0 * NT_H0;
#pragma unroll
  for (int i = 0; i < NT_H0; ++i) o0[i] = fmaxf(acc0[i], 0.f);
  if (has2) {
    float* o1 = h0 + (size_t)(b0 + bl) * (C1 * NT_H0) + c1 * NT_H0;
#pragma unroll
    for (int i = 0; i < NT_H0; ++i) o1[i] = fmaxf(acc1[i], 0.f);
  }
}

// ------- Kernel 2: y0 = relu(relu(conv2_0(h0)) + (wd_0*x + bd_0)) -----------
#define NB2 4
__global__ __launch_bounds__(256) void k_y0(const float* __restrict__ x,
                                            const float* __restrict__ h0,
                                            const float* __restrict__ w2,
                                            const float* __restrict__ b2,
                                            const float* __restrict__ wd,
                                            const float* __restrict__ bd,
                                            float* __restrict__ y0) {
  __shared__ float hs[NB2 * C1 * NT_H0];    // 8400 floats = 33.6 KB
  __shared__ float xrs[NB2 * CIN * NT_Y0];  // 1080 floats
  const int b0 = blockIdx.x * NB2;
  const int tid = threadIdx.x;
  for (int idx = tid; idx < NB2 * C1 * NT_H0; idx += 256) {
    int b = idx / (C1 * NT_H0);
    int r = idx - b * (C1 * NT_H0);
    hs[idx] = h0[(size_t)(b0 + b) * (C1 * NT_H0) + r];
  }
  for (int idx = tid; idx < NB2 * CIN * NT_Y0; idx += 256) {
    int b = idx / (CIN * NT_Y0);
    int r = idx - b * (CIN * NT_Y0);
    int ci = r / NT_Y0;
    int j = r - ci * NT_Y0;
    xrs[idx] = x[(size_t)(b0 + b) * (CIN * LSEQ) + ci * LSEQ + T0 + 8 + 2 * j];
  }
  __syncthreads();
  const int bl = tid & (NB2 - 1);
  const int cg = tid >> 2;
  const float* hb = hs + bl * (C1 * NT_H0);
  const float* xb = xrs + bl * (CIN * NT_Y0);
  const int c0 = cg;
  const bool has2 = (cg < C1 - 64);
  const int c1 = has2 ? cg + 64 : cg;

  float acc0[NT_Y0], acc1[NT_Y0];
  const float bA = b2[c0], bB = b2[c1];
#pragma unroll
  for (int j = 0; j < NT_Y0; ++j) { acc0[j] = bA; acc1[j] = bB; }
  const float* wr0 = w2 + c0 * (C1 * KW);
  const float* wr1 = w2 + c1 * (C1 * KW);
  for (int ci = 0; ci < C1; ++ci) {
    float hr[NT_H0];
#pragma unroll
    for (int u = 0; u < NT_H0; ++u) hr[u] = hb[ci * NT_H0 + u];
#pragma unroll
    for (int k = 0; k < KW; ++k) {
      const float wa = wr0[ci * KW + k];
      const float wb = wr1[ci * KW + k];
#pragma unroll
      for (int j = 0; j < NT_Y0; ++j) {
        acc0[j] = fmaf(hr[2 * j + k], wa, acc0[j]);
        acc1[j] = fmaf(hr[2 * j + k], wb, acc1[j]);
      }
    }
  }
  // 1x1 residual from x
  float r0[NT_Y0], r1[NT_Y0];
  const float dA = bd[c0], dB = bd[c1];
#pragma unroll
  for (int j = 0; j < NT_Y0; ++j) { r0[j] = dA; r1[j] = dB; }
  const float* wd0 = wd + c0 * CIN;
  const float* wd1 = wd + c1 * CIN;
  for (int ci = 0; ci < CIN; ++ci) {
    const float wa = wd0[ci], wb = wd1[ci];
#pragma unroll
    for (int j = 0; j < NT_Y0; ++j) {
      const float xv = xb[ci * NT_Y0 + j];
      r0[j] = fmaf(xv, wa, r0[j]);
      r1[j] = fmaf(xv, wb, r1[j]);
    }
  }
  float* o0 = y0 + (size_t)(b0 + bl) * (C1 * NT_Y0) + c0 * NT_Y0;
#pragma unroll
  for (int j = 0; j < NT_Y0; ++j) o0[j] = fmaxf(fmaxf(acc0[j], 0.f) + r0[j], 0.f);
  if (has2) {
    float* o1 = y0 + (size_t)(b0 + bl) * (C1 * NT_Y0) + c1 * NT_Y0;
#pragma unroll
    for (int j = 0; j < NT_Y0; ++j) o1[j] = fmaxf(fmaxf(acc1[j], 0.f) + r1[j], 0.f);
  }
}

// ------------- Kernel 3: h1 = relu(conv1_1(y0)), dilation 2 -----------------
#define NB3 4
__global__ __launch_bounds__(256) void k_h1(const float* __restrict__ y0,
                                            const float* __restrict__ w1,
                                            const float* __restrict__ b1,
                                            float* __restrict__ h1) {
  __shared__ float ys[NB3 * C1 * NT_Y0];  // 3600 floats
  const int b0 = blockIdx.x * NB3;
  const int tid = threadIdx.x;
  for (int idx = tid; idx < NB3 * C1 * NT_Y0; idx += 256) {
    int b = idx / (C1 * NT_Y0);
    int r = idx - b * (C1 * NT_Y0);
    ys[idx] = y0[(size_t)(b0 + b) * (C1 * NT_Y0) + r];
  }
  __syncthreads();
  const int bl = tid & 3;
  const int cg = tid >> 2;  // 0..63
  const float* yb = ys + bl * (C1 * NT_Y0);
  int cidx[4];
  bool valid[4];
#pragma unroll
  for (int m = 0; m < 4; ++m) {
    int c = cg + 64 * m;
    valid[m] = (c < C2);
    cidx[m] = valid[m] ? c : cg;
  }
  float acc[4][NT_H1];
#pragma unroll
  for (int m = 0; m < 4; ++m) {
    const float bb = b1[cidx[m]];
#pragma unroll
    for (int t = 0; t < NT_H1; ++t) acc[m][t] = bb;
  }
  const float* wp[4];
#pragma unroll
  for (int m = 0; m < 4; ++m) wp[m] = w1 + (size_t)cidx[m] * (C1 * KW);
  for (int ci = 0; ci < C1; ++ci) {
    float yr[NT_Y0];
#pragma unroll
    for (int u = 0; u < NT_Y0; ++u) yr[u] = yb[ci * NT_Y0 + u];
#pragma unroll
    for (int k = 0; k < KW; ++k) {
#pragma unroll
      for (int m = 0; m < 4; ++m) {
        const float w = wp[m][ci * KW + k];
#pragma unroll
        for (int t = 0; t < NT_H1; ++t) acc[m][t] = fmaf(yr[t + k], w, acc[m][t]);
      }
    }
  }
#pragma unroll
  for (int m = 0; m < 4; ++m) {
    if (valid[m]) {
      float* o = h1 + (size_t)(b0 + bl) * (C2 * NT_H1) + cidx[m] * NT_H1;
#pragma unroll
      for (int t = 0; t < NT_H1; ++t) o[t] = fmaxf(acc[m][t], 0.f);
    }
  }
}

// --- Kernel 4: y1 = relu(relu(conv2_1(h1)) + res1), then per-task head ------
#define NB4 8
#define NCH4 7  // ceil(200/32) channels per cg-group
__global__ __launch_bounds__(256) void k_out(const float* __restrict__ y0,
                                             const float* __restrict__ h1,
                                             const float* __restrict__ w2,
                                             const float* __restrict__ b2,
                                             const float* __restrict__ wd,
                                             const float* __restrict__ bd,
                                             const int* __restrict__ labels,
                                             const float* __restrict__ hw1,
                                             const float* __restrict__ hb1,
                                             const float* __restrict__ hw2,
                                             const float* __restrict__ hb2,
                                             float* __restrict__ out) {
  __shared__ float h1s[NB4 * C2 * NT_H1];  // 8000 floats = 32 KB
  __shared__ float y8s[NB4 * C1];          // y0[:, :, j=8] (t=255)
  __shared__ float feat[NB4 * C2];
  __shared__ float part[32 * NB4];
  const int b0 = blockIdx.x * NB4;
  const int tid = threadIdx.x;
  for (int idx = tid; idx < NB4 * C2 * NT_H1; idx += 256) {
    int b = idx / (C2 * NT_H1);
    int r = idx - b * (C2 * NT_H1);
    h1s[idx] = h1[(size_t)(b0 + b) * (C2 * NT_H1) + r];
  }
  for (int idx = tid; idx < NB4 * C1; idx += 256) {
    int b = idx / C1;
    int c = idx - b * C1;
    y8s[idx] = y0[(size_t)(b0 + b) * (C1 * NT_Y0) + c * NT_Y0 + 8];
  }
  __syncthreads();
  const int bl = tid & (NB4 - 1);
  const int cg = tid >> 3;  // 0..31
  const float* hb = h1s + bl * (C2 * NT_H1);
  const float* yb = y8s + bl * C1;
  int cidx[NCH4];
  bool valid[NCH4];
#pragma unroll
  for (int m = 0; m < NCH4; ++m) {
    int c = cg + 32 * m;
    valid[m] = (c < C2);
    cidx[m] = valid[m] ? c : cg;
  }
  float acc[NCH4];
#pragma unroll
  for (int m = 0; m < NCH4; ++m) acc[m] = b2[cidx[m]];
  for (int cH = 0; cH < C2; ++cH) {
    float h1r[NT_H1];
#pragma unroll
    for (int k = 0; k < NT_H1; ++k) h1r[k] = hb[cH * NT_H1 + k];
#pragma unroll
    for (int m = 0; m < NCH4; ++m) {
      const float* wr = w2 + (size_t)cidx[m] * (C2 * KW) + cH * KW;
#pragma unroll
      for (int k = 0; k < KW; ++k) acc[m] = fmaf(h1r[k], wr[k], acc[m]);
    }
  }
  float rs[NCH4];
#pragma unroll
  for (int m = 0; m < NCH4; ++m) rs[m] = bd[cidx[m]];
  for (int ci = 0; ci < C1; ++ci) {
    const float yv = yb[ci];
#pragma unroll
    for (int m = 0; m < NCH4; ++m) rs[m] = fmaf(yv, wd[cidx[m] * C1 + ci], rs[m]);
  }
#pragma unroll
  for (int m = 0; m < NCH4; ++m) {
    if (valid[m]) feat[bl * C2 + cidx[m]] = fmaxf(fmaxf(acc[m], 0.f) + rs[m], 0.f);
  }
  __syncthreads();
  // head: hid = tanh(feat @ W1[task]^T + B1); out = hid @ W2[task]^T + B2
  const int task = labels[b0 + bl];
  const float* fb = feat + bl * C2;
  float p = 0.f;
#pragma unroll
  for (int m = 0; m < 4; ++m) {
    const int o = cg + 32 * m;
    if (o < C1) {
      float a = hb1[task * C1 + o];
      const float* wr = hw1 + (size_t)task * (C1 * C2) + (size_t)o * C2;
      for (int d = 0; d < C2; ++d) a = fmaf(fb[d], wr[d], a);
      p = fmaf(tanhf(a), hw2[task * C1 + o], p);
    }
  }
  part[cg * NB4 + bl] = p;
  __syncthreads();
  if (tid < NB4) {
    const int task2 = labels[b0 + tid];
    float s = hb2[task2];
    for (int g = 0; g < 32; ++g) s += part[g * NB4 + tid];
    out[b0 + tid] = s;
  }
}

extern "C" void kernel_launch(void* const* d_in, const int* in_sizes, int n_in,
                              void* d_out, int out_size, void* d_ws, size_t ws_size,
                              hipStream_t stream) {
  const float* x    = (const float*)d_in[0];
  const int* labels = (const int*)d_in[1];
  const float* w1_0 = (const float*)d_in[2];
  const float* b1_0 = (const float*)d_in[3];
  const float* w2_0 = (const float*)d_in[4];
  const float* b2_0 = (const float*)d_in[5];
  const float* wd_0 = (const float*)d_in[6];
  const float* bd_0 = (const float*)d_in[7];
  const float* w1_1 = (const float*)d_in[8];
  const float* b1_1 = (const float*)d_in[9];
  const float* w2_1 = (const float*)d_in[10];
  const float* b2_1 = (const float*)d_in[11];
  const float* wd_1 = (const float*)d_in[12];
  const float* bd_1 = (const float*)d_in[13];
  const float* hw1  = (const float*)d_in[14];
  const float* hb1  = (const float*)d_in[15];
  const float* hw2  = (const float*)d_in[16];
  const float* hb2  = (const float*)d_in[17];
  float* out = (float*)d_out;

  // workspace: h0 (B*100*21) | y0 (B*100*9) | h1 (B*200*5)  = 65.5 MB total
  float* ws = (float*)d_ws;
  float* h0 = ws;
  float* y0 = h0 + (size_t)B_TOT * C1 * NT_H0;
  float* h1 = y0 + (size_t)B_TOT * C1 * NT_Y0;

  hipLaunchKernelGGL(k_h0, dim3(B_TOT / NB1), dim3(256), 0, stream, x, w1_0, b1_0, h0);
  hipLaunchKernelGGL(k_y0, dim3(B_TOT / NB2), dim3(256), 0, stream, x, h0, w2_0, b2_0, wd_0, bd_0, y0);
  hipLaunchKernelGGL(k_h1, dim3(B_TOT / NB3), dim3(256), 0, stream, y0, w1_1, b1_1, h1);
  hipLaunchKernelGGL(k_out, dim3(B_TOT / NB4), dim3(256), 0, stream, y0, h1, w2_1, b2_1,
                     wd_1, bd_1, labels, hw1, hb1, hw2, hb2, out);
}

// Round 3
// 596.285 us; speedup vs baseline: 1.1778x; 1.1778x over previous
//
#include <hip/hip_runtime.h>
#include <math.h>

// Batch-major redesign. Only y[:,:,-1] is consumed -> receptive-field window:
//   x 231..255 (25) -> h0 235..255 (21) -> y0 239..255 odd (9)
//   -> h1 247..255 odd (5) -> y1@255 -> head.   ~12.6 GFLOP.
// All intermediates transposed to [feature_row][batch] (batch stride-1,
// R=4096) so lane==batch gives coalesced loads; weights live in LDS
// transposed [kk][channel] and are read as wave-broadcast float4/float2.

#define R     4096
#define CIN   30
#define LSEQ  256
#define C1    100
#define C2    200
#define KW    5
#define T0    231
#define WIN   25
#define NU0   21
#define NJ0   9
#define NT1   5

// ws row offsets (units of R floats; each row = 16 KB)
#define ROW_XT    0      // 750 rows
#define ROW_H0T   750    // 2100 rows
#define ROW_Y0T   2850   // 900 rows
#define ROW_H1T   0      // 1000 rows, aliases xT+h0T-head (dead before K3)
#define ROW_FEAT  3750   // 200 rows  -> total 3950 rows = 64.7 MB

// ---------------- K0: transpose x window -> xT[(ci*25+u)][b] ----------------
__global__ __launch_bounds__(1024) void k_tr(const float* __restrict__ x,
                                             float* __restrict__ xT) {
  const int l = threadIdx.x & 63;
  const int wv = threadIdx.x >> 6;  // 0..15
  const int b = blockIdx.x * 64 + l;
  const float* xb = x + (size_t)b * (CIN * LSEQ) + T0;
  for (int r = wv; r < CIN * WIN; r += 16) {
    const int ci = r / WIN;
    const int u = r - ci * WIN;
    xT[(size_t)r * R + b] = xb[ci * LSEQ + u];  // coalesced store
  }
}

// ------------- K1: h0T[(c*21+u)][b] = relu(conv1_0), K=(30ci,5k) ------------
__global__ __launch_bounds__(256) void k1(const float* __restrict__ xT,
                                          const float* __restrict__ w1,
                                          const float* __restrict__ b1,
                                          float* __restrict__ h0T) {
  __shared__ float wT[CIN * KW * 16];  // [kk][cl], 9.6 KB
  const int tid = threadIdx.x;
  const int ctile = blockIdx.y * 16;
  for (int idx = tid; idx < CIN * KW * 16; idx += 256) {
    const int kk = idx >> 4, cl = idx & 15, c = ctile + cl;
    wT[idx] = (c < C1) ? w1[c * (CIN * KW) + kk] : 0.f;
  }
  __syncthreads();
  const int l = tid & 63, wv = tid >> 6;
  const int b = blockIdx.x * 64 + l;
  const int cb = ctile + wv * 4;
  float acc[4][NU0];
#pragma unroll
  for (int m = 0; m < 4; ++m) {
    const float bias = (cb + m < C1) ? b1[cb + m] : 0.f;
#pragma unroll
    for (int u = 0; u < NU0; ++u) acc[m][u] = bias;
  }
  for (int ci = 0; ci < CIN; ++ci) {
    float xr[WIN];
    const float* xp = xT + (size_t)ci * WIN * R + b;
#pragma unroll
    for (int u = 0; u < WIN; ++u) xr[u] = xp[(size_t)u * R];
#pragma unroll
    for (int k = 0; k < KW; ++k) {
      const float4 w = *reinterpret_cast<const float4*>(&wT[(ci * KW + k) * 16 + wv * 4]);
#pragma unroll
      for (int u = 0; u < NU0; ++u) {
        acc[0][u] = fmaf(xr[u + k], w.x, acc[0][u]);
        acc[1][u] = fmaf(xr[u + k], w.y, acc[1][u]);
        acc[2][u] = fmaf(xr[u + k], w.z, acc[2][u]);
        acc[3][u] = fmaf(xr[u + k], w.w, acc[3][u]);
      }
    }
  }
#pragma unroll
  for (int m = 0; m < 4; ++m) {
    const int c = cb + m;
    if (c < C1) {
#pragma unroll
      for (int u = 0; u < NU0; ++u)
        h0T[(size_t)(c * NU0 + u) * R + b] = fmaxf(acc[m][u], 0.f);
    }
  }
}

// --- K2: y0T[(c*9+j)][b] = relu(relu(conv2_0) + wd_0*x + bd_0), K=500+30 ----
__global__ __launch_bounds__(256) void k2(const float* __restrict__ xT,
                                          const float* __restrict__ h0T,
                                          const float* __restrict__ w2,
                                          const float* __restrict__ b2,
                                          const float* __restrict__ wd,
                                          const float* __restrict__ bd,
                                          float* __restrict__ y0T) {
  __shared__ float wT[C1 * KW * 16];  // 32 KB
  __shared__ float wdT[CIN * 16];     // 1.9 KB
  const int tid = threadIdx.x;
  const int ctile = blockIdx.y * 16;
  for (int idx = tid; idx < C1 * KW * 16; idx += 256) {
    const int kk = idx >> 4, cl = idx & 15, c = ctile + cl;
    wT[idx] = (c < C1) ? w2[c * (C1 * KW) + kk] : 0.f;
  }
  for (int idx = tid; idx < CIN * 16; idx += 256) {
    const int ci = idx >> 4, cl = idx & 15, c = ctile + cl;
    wdT[idx] = (c < C1) ? wd[c * CIN + ci] : 0.f;
  }
  __syncthreads();
  const int l = tid & 63, wv = tid >> 6;
  const int b = blockIdx.x * 64 + l;
  const int cb = ctile + wv * 4;
  float acc[4][NJ0], rac[4][NJ0];
#pragma unroll
  for (int m = 0; m < 4; ++m) {
    const float bias = (cb + m < C1) ? b2[cb + m] : 0.f;
    const float bres = (cb + m < C1) ? bd[cb + m] : 0.f;
#pragma unroll
    for (int j = 0; j < NJ0; ++j) { acc[m][j] = bias; rac[m][j] = bres; }
  }
  for (int ci = 0; ci < C1; ++ci) {
    float hr[NU0];
    const float* hp = h0T + (size_t)ci * NU0 * R + b;
#pragma unroll
    for (int u = 0; u < NU0; ++u) hr[u] = hp[(size_t)u * R];
#pragma unroll
    for (int k = 0; k < KW; ++k) {
      const float4 w = *reinterpret_cast<const float4*>(&wT[(ci * KW + k) * 16 + wv * 4]);
#pragma unroll
      for (int j = 0; j < NJ0; ++j) {
        acc[0][j] = fmaf(hr[2 * j + k], w.x, acc[0][j]);
        acc[1][j] = fmaf(hr[2 * j + k], w.y, acc[1][j]);
        acc[2][j] = fmaf(hr[2 * j + k], w.z, acc[2][j]);
        acc[3][j] = fmaf(hr[2 * j + k], w.w, acc[3][j]);
      }
    }
  }
  for (int ci = 0; ci < CIN; ++ci) {
    float xr[NJ0];
    const float* xp = xT + (size_t)(ci * WIN + 8) * R + b;
#pragma unroll
    for (int j = 0; j < NJ0; ++j) xr[j] = xp[(size_t)(2 * j) * R];
    const float4 w = *reinterpret_cast<const float4*>(&wdT[ci * 16 + wv * 4]);
#pragma unroll
    for (int j = 0; j < NJ0; ++j) {
      rac[0][j] = fmaf(xr[j], w.x, rac[0][j]);
      rac[1][j] = fmaf(xr[j], w.y, rac[1][j]);
      rac[2][j] = fmaf(xr[j], w.z, rac[2][j]);
      rac[3][j] = fmaf(xr[j], w.w, rac[3][j]);
    }
  }
#pragma unroll
  for (int m = 0; m < 4; ++m) {
    const int c = cb + m;
    if (c < C1) {
#pragma unroll
      for (int j = 0; j < NJ0; ++j)
        y0T[(size_t)(c * NJ0 + j) * R + b] =
            fmaxf(fmaxf(acc[m][j], 0.f) + rac[m][j], 0.f);
    }
  }
}

// ---------- K3: h1T[(c*5+t)][b] = relu(conv1_1 dil2), K=(100ci,5k) ----------
__global__ __launch_bounds__(256) void k3(const float* __restrict__ y0T,
                                          const float* __restrict__ w1,
                                          const float* __restrict__ b1,
                                          float* __restrict__ h1T) {
  __shared__ float wT[C1 * KW * 16];  // 32 KB
  const int tid = threadIdx.x;
  const int ctile = blockIdx.y * 16;
  for (int idx = tid; idx < C1 * KW * 16; idx += 256) {
    const int kk = idx >> 4, cl = idx & 15, c = ctile + cl;
    wT[idx] = (c < C2) ? w1[c * (C1 * KW) + kk] : 0.f;
  }
  __syncthreads();
  const int l = tid & 63, wv = tid >> 6;
  const int b = blockIdx.x * 64 + l;
  const int cb = ctile + wv * 4;
  float acc[4][NT1];
#pragma unroll
  for (int m = 0; m < 4; ++m) {
    const float bias = (cb + m < C2) ? b1[cb + m] : 0.f;
#pragma unroll
    for (int t = 0; t < NT1; ++t) acc[m][t] = bias;
  }
  for (int ci = 0; ci < C1; ++ci) {
    float yr[NJ0];
    const float* yp = y0T + (size_t)ci * NJ0 * R + b;
#pragma unroll
    for (int u = 0; u < NJ0; ++u) yr[u] = yp[(size_t)u * R];
#pragma unroll
    for (int k = 0; k < KW; ++k) {
      const float4 w = *reinterpret_cast<const float4*>(&wT[(ci * KW + k) * 16 + wv * 4]);
#pragma unroll
      for (int t = 0; t < NT1; ++t) {
        acc[0][t] = fmaf(yr[t + k], w.x, acc[0][t]);
        acc[1][t] = fmaf(yr[t + k], w.y, acc[1][t]);
        acc[2][t] = fmaf(yr[t + k], w.z, acc[2][t]);
        acc[3][t] = fmaf(yr[t + k], w.w, acc[3][t]);
      }
    }
  }
#pragma unroll
  for (int m = 0; m < 4; ++m) {
    const int c = cb + m;
    if (c < C2) {
#pragma unroll
      for (int t = 0; t < NT1; ++t)
        h1T[(size_t)(c * NT1 + t) * R + b] = fmaxf(acc[m][t], 0.f);
    }
  }
}

// ------ K4a: featT[c][b] = relu(relu(conv2_1@255) + res), K=1000(+100) ------
__global__ __launch_bounds__(256) void k4a(const float* __restrict__ h1T,
                                           const float* __restrict__ y0T,
                                           const float* __restrict__ w2,
                                           const float* __restrict__ b2,
                                           const float* __restrict__ wd,
                                           const float* __restrict__ bd,
                                           float* __restrict__ featT) {
  __shared__ float wT[C2 * KW * 8];  // [kk][cl], 32 KB
  __shared__ float wdT[C1 * 8];      // 3.2 KB
  const int tid = threadIdx.x;
  const int cb8 = blockIdx.y * 8;  // 25 tiles x 8 = 200, exact
  for (int idx = tid; idx < C2 * KW * 8; idx += 256) {
    const int kk = idx >> 3, cl = idx & 7;
    wT[idx] = w2[(cb8 + cl) * (C2 * KW) + kk];
  }
  for (int idx = tid; idx < C1 * 8; idx += 256) {
    const int ci = idx >> 3, cl = idx & 7;
    wdT[idx] = wd[(cb8 + cl) * C1 + ci];
  }
  __syncthreads();
  const int l = tid & 63, wv = tid >> 6;
  const int b4 = blockIdx.x * 256 + l * 4;
  const int c0 = cb8 + wv * 2;
  float a0[4], a1[4], r0[4], r1[4];
  {
    const float bA = b2[c0], bB = b2[c0 + 1];
    const float dA = bd[c0], dB = bd[c0 + 1];
#pragma unroll
    for (int m = 0; m < 4; ++m) { a0[m] = bA; a1[m] = bB; r0[m] = dA; r1[m] = dB; }
  }
#pragma unroll 4
  for (int kk = 0; kk < C2 * KW; ++kk) {
    const float4 h = *reinterpret_cast<const float4*>(&h1T[(size_t)kk * R + b4]);
    const float2 w = *reinterpret_cast<const float2*>(&wT[kk * 8 + wv * 2]);
    a0[0] = fmaf(h.x, w.x, a0[0]); a0[1] = fmaf(h.y, w.x, a0[1]);
    a0[2] = fmaf(h.z, w.x, a0[2]); a0[3] = fmaf(h.w, w.x, a0[3]);
    a1[0] = fmaf(h.x, w.y, a1[0]); a1[1] = fmaf(h.y, w.y, a1[1]);
    a1[2] = fmaf(h.z, w.y, a1[2]); a1[3] = fmaf(h.w, w.y, a1[3]);
  }
#pragma unroll 4
  for (int ci = 0; ci < C1; ++ci) {
    const float4 y = *reinterpret_cast<const float4*>(&y0T[(size_t)(ci * NJ0 + 8) * R + b4]);
    const float2 w = *reinterpret_cast<const float2*>(&wdT[ci * 8 + wv * 2]);
    r0[0] = fmaf(y.x, w.x, r0[0]); r0[1] = fmaf(y.y, w.x, r0[1]);
    r0[2] = fmaf(y.z, w.x, r0[2]); r0[3] = fmaf(y.w, w.x, r0[3]);
    r1[0] = fmaf(y.x, w.y, r1[0]); r1[1] = fmaf(y.y, w.y, r1[1]);
    r1[2] = fmaf(y.z, w.y, r1[2]); r1[3] = fmaf(y.w, w.y, r1[3]);
  }
  float4 f0, f1;
  f0.x = fmaxf(fmaxf(a0[0], 0.f) + r0[0], 0.f);
  f0.y = fmaxf(fmaxf(a0[1], 0.f) + r0[1], 0.f);
  f0.z = fmaxf(fmaxf(a0[2], 0.f) + r0[2], 0.f);
  f0.w = fmaxf(fmaxf(a0[3], 0.f) + r0[3], 0.f);
  f1.x = fmaxf(fmaxf(a1[0], 0.f) + r1[0], 0.f);
  f1.y = fmaxf(fmaxf(a1[1], 0.f) + r1[1], 0.f);
  f1.z = fmaxf(fmaxf(a1[2], 0.f) + r1[2], 0.f);
  f1.w = fmaxf(fmaxf(a1[3], 0.f) + r1[3], 0.f);
  *reinterpret_cast<float4*>(&featT[(size_t)c0 * R + b4]) = f0;
  *reinterpret_cast<float4*>(&featT[(size_t)(c0 + 1) * R + b4]) = f1;
}

// -------- K4b: per-batch head, one wave per item, feat in LDS ---------------
__global__ __launch_bounds__(256) void k4b(const float* __restrict__ featT,
                                           const int* __restrict__ labels,
                                           const float* __restrict__ hw1,
                                           const float* __restrict__ hb1,
                                           const float* __restrict__ hw2,
                                           const float* __restrict__ hb2,
                                           float* __restrict__ out) {
  __shared__ float fs[4][C2];
  const int tid = threadIdx.x;
  const int b0 = blockIdx.x * 4;
  for (int idx = tid; idx < 4 * C2; idx += 256) {
    const int c = idx >> 2, bi = idx & 3;
    fs[bi][c] = featT[(size_t)c * R + b0 + bi];
  }
  __syncthreads();
  const int l = tid & 63, wv = tid >> 6;
  const int b = b0 + wv;
  const int task = labels[b];
  const float* W1 = hw1 + (size_t)task * (C1 * C2);
  const float* fp = fs[wv];
  float p = 0.f;
  {  // o = l  (all lanes, l < 100)
    float a = hb1[task * C1 + l];
    const float* wr = W1 + (size_t)l * C2;
#pragma unroll 4
    for (int d = 0; d < C2; d += 4) {
      const float4 fv = *reinterpret_cast<const float4*>(&fp[d]);
      const float4 wv4 = *reinterpret_cast<const float4*>(&wr[d]);
      a = fmaf(fv.x, wv4.x, a); a = fmaf(fv.y, wv4.y, a);
      a = fmaf(fv.z, wv4.z, a); a = fmaf(fv.w, wv4.w, a);
    }
    p = tanhf(a) * hw2[task * C1 + l];
  }
  if (l < C1 - 64) {  // o = 64 + l
    const int o = 64 + l;
    float a = hb1[task * C1 + o];
    const float* wr = W1 + (size_t)o * C2;
#pragma unroll 4
    for (int d = 0; d < C2; d += 4) {
      const float4 fv = *reinterpret_cast<const float4*>(&fp[d]);
      const float4 wv4 = *reinterpret_cast<const float4*>(&wr[d]);
      a = fmaf(fv.x, wv4.x, a); a = fmaf(fv.y, wv4.y, a);
      a = fmaf(fv.z, wv4.z, a); a = fmaf(fv.w, wv4.w, a);
    }
    p = fmaf(tanhf(a), hw2[task * C1 + o], p);
  }
#pragma unroll
  for (int off = 32; off > 0; off >>= 1) p += __shfl_down(p, off, 64);
  if (l == 0) out[b] = p + hb2[task];
}

extern "C" void kernel_launch(void* const* d_in, const int* in_sizes, int n_in,
                              void* d_out, int out_size, void* d_ws, size_t ws_size,
                              hipStream_t stream) {
  const float* x    = (const float*)d_in[0];
  const int* labels = (const int*)d_in[1];
  const float* w1_0 = (const float*)d_in[2];
  const float* b1_0 = (const float*)d_in[3];
  const float* w2_0 = (const float*)d_in[4];
  const float* b2_0 = (const float*)d_in[5];
  const float* wd_0 = (const float*)d_in[6];
  const float* bd_0 = (const float*)d_in[7];
  const float* w1_1 = (const float*)d_in[8];
  const float* b1_1 = (const float*)d_in[9];
  const float* w2_1 = (const float*)d_in[10];
  const float* b2_1 = (const float*)d_in[11];
  const float* wd_1 = (const float*)d_in[12];
  const float* bd_1 = (const float*)d_in[13];
  const float* hw1  = (const float*)d_in[14];
  const float* hb1  = (const float*)d_in[15];
  const float* hw2  = (const float*)d_in[16];
  const float* hb2  = (const float*)d_in[17];
  float* out = (float*)d_out;

  float* ws    = (float*)d_ws;
  float* xT    = ws + (size_t)ROW_XT * R;
  float* h0T   = ws + (size_t)ROW_H0T * R;
  float* y0T   = ws + (size_t)ROW_Y0T * R;
  float* h1T   = ws + (size_t)ROW_H1T * R;   // aliases xT/h0T (dead by K3)
  float* featT = ws + (size_t)ROW_FEAT * R;

  hipLaunchKernelGGL(k_tr, dim3(64), dim3(1024), 0, stream, x, xT);
  hipLaunchKernelGGL(k1, dim3(64, 7), dim3(256), 0, stream, xT, w1_0, b1_0, h0T);
  hipLaunchKernelGGL(k2, dim3(64, 7), dim3(256), 0, stream, xT, h0T, w2_0, b2_0, wd_0, bd_0, y0T);
  hipLaunchKernelGGL(k3, dim3(64, 13), dim3(256), 0, stream, y0T, w1_1, b1_1, h1T);
  hipLaunchKernelGGL(k4a, dim3(16, 25), dim3(256), 0, stream, h1T, y0T, w2_1, b2_1, wd_1, bd_1, featT);
  hipLaunchKernelGGL(k4b, dim3(1024), dim3(256), 0, stream, featT, labels,
                     hw1, hb1, hw2, hb2, out);
}